// Round 12
// baseline (387.583 us; speedup 1.0000x reference)
//
#include <hip/hip_runtime.h>
#include <hip/hip_bf16.h>
#include <hip/hip_fp16.h>

// Pipeline:
//  x (4,64,130,130) --conv3x3 valid + bias + maxpool2x2--> p1 (4,64,64,64)
//  p1 --1x1 conv (64->32)--> t2 (4,32,64,64)
//  t2 --3x3 conv pad=1 (32->32)--> t3 (4,32,64,64)
//  t3 --1x1 conv (32->1152)--> t4h[b][strip][chunk][ckk][16 po]  fp16 (oy,ox)
//  deform_conv(x, upsample2x(offsets), wd) -> out (4,64,128,128)
//  Deform: block = 16-po strip (64 out px). Phase-1 computes bilinear samples
//  once per (quad,ch,kk), converts to bf16 into an MFMA-A-layout LDS tile.
//  Phase-2 = D[64px][64oc] += V·W^T via v_mfma_f32_16x16x32_bf16 (2 sups x
//  9 K-steps x 4 N-tiles). Weights pre-cast to bf16 k-major (L2-resident).

#define HX 130
#define WX 130

typedef short bf16x8 __attribute__((ext_vector_type(8)));
typedef float f32x4 __attribute__((ext_vector_type(4)));

static __device__ __forceinline__ unsigned short f2bf(float f) {
    unsigned u = __float_as_uint(f);
    unsigned r = u + 0x7fff + ((u >> 16) & 1);   // round-to-nearest-even
    return (unsigned short)(r >> 16);
}

// ---------------- K0: wd (o,c,3,3) -> bf16 wdtb[sup(2)][oc(64)][k_local(288)]
// k_local = cw*72 + ch*9 + kk  for c = sup*32 + cw*8 + ch  (matches deform A cols)
__global__ __launch_bounds__(256) void k_wdt(const float* __restrict__ wd,
                                             unsigned short* __restrict__ wdtb) {
    int idx = blockIdx.x * 256 + threadIdx.x;   // 64*64*9 = 36864
    if (idx >= 36864) return;
    int o = idx / 576;
    int rem = idx - o * 576;
    int c = rem / 9;
    int kk = rem - c * 9;
    int sup = c >> 5, ci = c & 31;
    int kl = (ci >> 3) * 72 + (ci & 7) * 9 + kk;
    wdtb[(size_t)(sup * 64 + o) * 288 + kl] = f2bf(wd[idx]);
}

// ---------------- K1: conv3x3 valid (64->64) + bias + maxpool 2x2 -> p1
// grid 1024 = b(4) * cog(16, 4 oc) * tile(16, 4 pooled rows); block 256
__global__ __launch_bounds__(256, 4) void k_conv0_pool(const float* __restrict__ x,
                                                       const float* __restrict__ w0,
                                                       const float* __restrict__ b0,
                                                       float* __restrict__ p1) {
    int idx = blockIdx.x;
    int tile = idx & 15;          // 4 pooled rows each
    int cog = (idx >> 4) & 15;    // blockIdx-derived -> weight loads scalar
    int b = idx >> 8;
    int tid = threadIdx.x;
    int pw = tid & 63;
    int phl = tid >> 6;           // 0..3
    int ph = tile * 4 + phl;
    __shared__ float slab[2][10 * WX];        // 2 ci x 1300 floats
    const float* xb = x + (size_t)(b * 64) * HX * WX;
    int row0 = tile * 8;          // x rows row0..row0+9
    const float* xbase = xb + row0 * WX;
    float acc[4][4];
    #pragma unroll
    for (int i = 0; i < 4; ++i)
        #pragma unroll
        for (int j = 0; j < 4; ++j) acc[i][j] = 0.f;

    float pre[11];
    #pragma unroll
    for (int j = 0; j < 11; ++j) {
        int i = tid + j * 256;    // 0..2599 covers both ci slabs
        int ci = i / 1300, off = i - ci * 1300;
        pre[j] = (i < 2600) ? xbase[(size_t)ci * (HX * WX) + off] : 0.f;
    }

    for (int cg = 0; cg < 32; ++cg) {         // 2 ci per stage
        __syncthreads();
        #pragma unroll
        for (int j = 0; j < 11; ++j) {
            int i = tid + j * 256;
            if (i < 2600) ((float*)slab)[i] = pre[j];
        }
        __syncthreads();
        if (cg < 31) {
            const float* xp = xbase + (size_t)(2 * cg + 2) * (HX * WX);
            #pragma unroll
            for (int j = 0; j < 11; ++j) {
                int i = tid + j * 256;
                int ci = i / 1300, off = i - ci * 1300;
                pre[j] = (i < 2600) ? xp[(size_t)ci * (HX * WX) + off] : 0.f;
            }
        }
        #pragma unroll
        for (int lc = 0; lc < 2; ++lc) {
            int ci = 2 * cg + lc;
            float v[4][4];
            #pragma unroll
            for (int r2 = 0; r2 < 4; ++r2) {
                const float* rp = &slab[lc][(2 * phl + r2) * WX + 2 * pw];
                float2 a = *(const float2*)rp;
                float2 bb = *(const float2*)(rp + 2);
                v[r2][0] = a.x; v[r2][1] = a.y; v[r2][2] = bb.x; v[r2][3] = bb.y;
            }
            #pragma unroll
            for (int i = 0; i < 4; ++i) {
                const float* wp = w0 + (((cog * 4 + i) * 64) + ci) * 9;  // uniform
                float w[9];
                #pragma unroll
                for (int k = 0; k < 9; ++k) w[k] = wp[k];
                #pragma unroll
                for (int dr = 0; dr < 2; ++dr)
                    #pragma unroll
                    for (int dc = 0; dc < 2; ++dc) {
                        float s = acc[i][dr * 2 + dc];
                        #pragma unroll
                        for (int ky = 0; ky < 3; ++ky)
                            #pragma unroll
                            for (int kx = 0; kx < 3; ++kx)
                                s += w[ky * 3 + kx] * v[dr + ky][dc + kx];
                        acc[i][dr * 2 + dc] = s;
                    }
            }
        }
    }
    #pragma unroll
    for (int i = 0; i < 4; ++i) {
        float m = fmaxf(fmaxf(acc[i][0], acc[i][1]), fmaxf(acc[i][2], acc[i][3]))
                + b0[cog * 4 + i];
        p1[(((size_t)b * 64 + cog * 4 + i) * 64 + ph) * 64 + pw] = m;
    }
}

// ---------------- K2: 1x1 conv 64->32 on 64x64; grid 1024 (2 oc/thread)
__global__ __launch_bounds__(256) void k_conv1x1_a(const float* __restrict__ p1,
                                                   const float* __restrict__ w1,
                                                   const float* __restrict__ b1,
                                                   float* __restrict__ t2) {
    int blk = blockIdx.x;
    int pt = blk & 15;
    int cog = (blk >> 4) & 15;
    int b = blk >> 8;
    int p = pt * 256 + threadIdx.x;
    float acc[2];
    #pragma unroll
    for (int i = 0; i < 2; ++i) acc[i] = b1[cog * 2 + i];
    const float* ip = p1 + (size_t)b * 64 * 4096 + p;
    for (int ci = 0; ci < 64; ++ci) {
        float v = ip[(size_t)ci * 4096];
        #pragma unroll
        for (int i = 0; i < 2; ++i) acc[i] += w1[(cog * 2 + i) * 64 + ci] * v;
    }
    float* op = t2 + (size_t)b * 32 * 4096 + p;
    #pragma unroll
    for (int i = 0; i < 2; ++i) op[(size_t)(cog * 2 + i) * 4096] = acc[i];
}

// ---------------- K3: 3x3 conv pad=1, 32->32 on 64x64; grid 1024 (2 oc/thread)
__global__ __launch_bounds__(256) void k_conv3x3_b(const float* __restrict__ t2,
                                                   const float* __restrict__ w2,
                                                   const float* __restrict__ b2,
                                                   float* __restrict__ t3) {
    int blk = blockIdx.x;
    int pt = blk & 15;
    int cog = (blk >> 4) & 15;
    int b = blk >> 8;
    int p = pt * 256 + threadIdx.x;
    int hy = p >> 6, wx = p & 63;
    float acc[2];
    #pragma unroll
    for (int i = 0; i < 2; ++i) acc[i] = b2[cog * 2 + i];
    const float* ip = t2 + (size_t)b * 32 * 4096;
    for (int ci = 0; ci < 32; ++ci) {
        float v[9];
        #pragma unroll
        for (int ky = 0; ky < 3; ++ky) {
            int yy = hy + ky - 1;
            #pragma unroll
            for (int kx = 0; kx < 3; ++kx) {
                int xx = wx + kx - 1;
                bool ok = (yy >= 0 && yy < 64 && xx >= 0 && xx < 64);
                int yc = min(max(yy, 0), 63), xc = min(max(xx, 0), 63);
                float val = ip[(size_t)ci * 4096 + yc * 64 + xc];
                v[ky * 3 + kx] = ok ? val : 0.f;
            }
        }
        #pragma unroll
        for (int i = 0; i < 2; ++i) {
            const float* wp = w2 + (((cog * 2 + i) * 32) + ci) * 9;   // uniform
            float s = acc[i];
            #pragma unroll
            for (int k = 0; k < 9; ++k) s += wp[k] * v[k];
            acc[i] = s;
        }
    }
    float* op = t3 + (size_t)b * 32 * 4096 + p;
    #pragma unroll
    for (int i = 0; i < 2; ++i) op[(size_t)(cog * 2 + i) * 4096] = acc[i];
}

// ---------------- K4: 1x1 conv 32->1152 -> fp16 (oy,ox)-paired strip-blocked
// t4h[b][strip][chunk(8)][ckk(72)][po(16)] as __half2.  grid 4608.
__global__ __launch_bounds__(256) void k_conv1x1_off(const float* __restrict__ t3,
                                                     const float* __restrict__ w3,
                                                     const float* __restrict__ b3,
                                                     __half2* __restrict__ t4h) {
    int blk = blockIdx.x;
    int pt = blk & 15;
    int rem = blk >> 4;           // 0..287
    int chg = rem % 72;           // blockIdx-derived -> scalar weight loads
    int b = rem / 72;
    int p = pt * 256 + threadIdx.x;
    float v[32];
    const float* ip = t3 + (size_t)b * 32 * 4096 + p;
    #pragma unroll
    for (int ci = 0; ci < 32; ++ci) v[ci] = ip[(size_t)ci * 4096];
    int strip = p >> 4, pl = p & 15;
    __half2* base = t4h + (size_t)(b * 256 + strip) * 9216;   // 8*1152 half2
    #pragma unroll
    for (int m = 0; m < 8; ++m) {
        int chE = chg * 16 + 2 * m;
        float accE = b3[chE], accO = b3[chE + 1];
        const float* wpE = w3 + chE * 32;         // uniform
        const float* wpO = wpE + 32;
        #pragma unroll
        for (int ci = 0; ci < 32; ++ci) {
            accE += wpE[ci] * v[ci];
            accO += wpO[ci] * v[ci];
        }
        int gp = chg * 8 + m;                     // global pair 0..575
        int chunk = gp / 72;
        int ckk = gp - chunk * 72;
        base[chunk * 1152 + ckk * 16 + pl] = __floats2half2_rn(accE, accO);
    }
}

// ---------------- K5: deformable conv with MFMA phase-2
// grid 1024 = strip(256)*4 + b. block 256 = 4 waves; wave w <-> sub-pixel w.
// Phase-1: 4608 tasks/sup (18 x 256), bf16 samples -> alds[px=sub*16+q][k 288]
// (pitch 296 shorts: 2-way-free banks). Phase-2: 9 K-steps x 4 N-tiles of
// mfma_f32_16x16x32_bf16; B-frags straight from global (L2-resident 74 KB).
#define APK 296
__global__ __launch_bounds__(256, 4) void k_deform(const float* __restrict__ x,
                                                   const __half2* __restrict__ t4h,
                                                   const unsigned short* __restrict__ wdtb,
                                                   float* __restrict__ out) {
    int blk = blockIdx.x;
    int b = blk & 3;
    int strip = blk >> 2;         // 0..255
    int tid = threadIdx.x;
    int po0 = strip * 16;
    int qy = po0 >> 6;            // strip lies in one quad-row
    int qx0 = po0 & 63;
    int w = tid >> 6;             // wave id = sub-pixel
    int lane = tid & 63;
    int lm = lane & 15;
    int lq = lane >> 4;

    __shared__ unsigned short alds[64 * APK];   // 37888 B

    f32x4 acc[4];
    #pragma unroll
    for (int n = 0; n < 4; ++n) acc[n] = (f32x4){0.f, 0.f, 0.f, 0.f};

    const float* xb = x + (size_t)b * 64 * HX * WX;
    const __half2* osrc = t4h + (size_t)(b * 256 + strip) * 9216;
    const unsigned short* arow = alds + (w * 16 + lm) * APK + lq * 8;

    for (int sup = 0; sup < 2; ++sup) {
        __syncthreads();          // prev phase-2 done reading alds
        // hoisted offset loads: 4608 half2 = 18 full iters, fully coalesced
        __half2 o2h[18];
        #pragma unroll
        for (int j = 0; j < 18; ++j)
            o2h[j] = osrc[sup * 4608 + j * 256 + tid];

        // ---- phase 1: 4608 tasks (16 q x 288 k-cols)
        #pragma unroll
        for (int j = 0; j < 18; ++j) {
            int idx = j * 256 + tid;          // 0..4607
            int ckkg = idx >> 4;              // 0..287 = A column
            int tq = idx & 15;
            int cw = (ckkg * 114) >> 13;      // /72
            int r72 = ckkg - cw * 72;
            int ch = (r72 * 57) >> 9;         // /9
            int kk = r72 - ch * 9;
            int c = sup * 32 + cw * 8 + ch;
            float2 off = __half22float2(o2h[j]);
            float py = off.x + (float)(2 * qy + kk / 3);
            float px = off.y + (float)(2 * (qx0 + tq) + kk % 3);
            float y0f = floorf(py), x0f = floorf(px);
            float fy = py - y0f, fx = px - x0f;
            int y0 = (int)y0f, x0 = (int)x0f;
            const float* xp = xb + (size_t)c * (HX * WX);
            float t[3][3];
            #pragma unroll
            for (int r = 0; r < 3; ++r) {
                int yy = y0 + r;
                bool vy = (yy >= 0) & (yy < HX);
                int yc = min(max(yy, 0), HX - 1);
                #pragma unroll
                for (int sx = 0; sx < 3; ++sx) {
                    int xx = x0 + sx;
                    bool vx = (xx >= 0) & (xx < WX);
                    int xc = min(max(xx, 0), WX - 1);
                    float val = xp[yc * WX + xc];
                    t[r][sx] = (vy & vx) ? val : 0.f;
                }
            }
            float h0[3], h1[3];
            #pragma unroll
            for (int r = 0; r < 3; ++r) {
                h0[r] = t[r][0] + fx * (t[r][1] - t[r][0]);
                h1[r] = t[r][1] + fx * (t[r][2] - t[r][1]);
            }
            // 4 sub-pixel values -> rows sub*16+tq, col ckkg (bf16)
            alds[(0 * 16 + tq) * APK + ckkg] = f2bf(h0[0] + fy * (h0[1] - h0[0]));
            alds[(1 * 16 + tq) * APK + ckkg] = f2bf(h1[0] + fy * (h1[1] - h1[0]));
            alds[(2 * 16 + tq) * APK + ckkg] = f2bf(h0[1] + fy * (h0[2] - h0[1]));
            alds[(3 * 16 + tq) * APK + ckkg] = f2bf(h1[1] + fy * (h1[2] - h1[1]));
        }
        __syncthreads();          // alds visible

        // ---- phase 2: MFMA GEMM  D[64px][64oc] += V[64][288] . W^T
        const unsigned short* bsup = wdtb + (size_t)(sup * 64 + lm) * 288 + lq * 8;
        #pragma unroll
        for (int ks = 0; ks < 9; ++ks) {
            bf16x8 a = *(const bf16x8*)(arow + ks * 32);
            #pragma unroll
            for (int n = 0; n < 4; ++n) {
                bf16x8 bb = *(const bf16x8*)(bsup + (size_t)n * 16 * 288 + ks * 32);
                acc[n] = __builtin_amdgcn_mfma_f32_16x16x32_bf16(a, bb, acc[n], 0, 0, 0);
            }
        }
    }

    // ---- epilogue: D row = lq*4+reg = quad q, col = lm = oc within tile
    int ho = 2 * qy + (w >> 1);
    int wob = (w & 1);
    #pragma unroll
    for (int n = 0; n < 4; ++n) {
        int oc = n * 16 + lm;
        float* op = out + (((size_t)b * 64 + oc) * 128 + ho) * 128;
        #pragma unroll
        for (int r = 0; r < 4; ++r) {
            int q = lq * 4 + r;
            op[2 * (qx0 + q) + wob] = acc[n][r];
        }
    }
}

extern "C" void kernel_launch(void* const* d_in, const int* in_sizes, int n_in,
                              void* d_out, int out_size, void* d_ws, size_t ws_size,
                              hipStream_t stream) {
    const float* x  = (const float*)d_in[0];
    const float* w0 = (const float*)d_in[1];
    const float* b0 = (const float*)d_in[2];
    const float* w1 = (const float*)d_in[3];
    const float* b1 = (const float*)d_in[4];
    const float* w2 = (const float*)d_in[5];
    const float* b2 = (const float*)d_in[6];
    const float* w3 = (const float*)d_in[7];
    const float* b3 = (const float*)d_in[8];
    const float* wd = (const float*)d_in[9];
    float* out = (float*)d_out;

    float* ws = (float*)d_ws;
    float* p1    = ws;                       // 1,048,576 floats
    float* t2    = p1 + 1048576;             //   524,288
    float* t3    = t2 + 524288;              //   524,288
    __half2* t4h = (__half2*)(t3 + 524288);  // 9,437,184 half2 (37.7 MB)
    unsigned short* wdtb = (unsigned short*)(t4h + 9437184);  // 36,864 bf16

    k_wdt<<<144, 256, 0, stream>>>(wd, wdtb);
    k_conv0_pool<<<1024, 256, 0, stream>>>(x, w0, b0, p1);
    k_conv1x1_a<<<1024, 256, 0, stream>>>(p1, w1, b1, t2);
    k_conv3x3_b<<<1024, 256, 0, stream>>>(t2, w2, b2, t3);
    k_conv1x1_off<<<4608, 256, 0, stream>>>(t3, w3, b3, t4h);
    k_deform<<<1024, 256, 0, stream>>>(x, t4h, wdtb, out);
}

// Round 13
// 306.186 us; speedup vs baseline: 1.2658x; 1.2658x over previous
//
#include <hip/hip_runtime.h>
#include <hip/hip_bf16.h>
#include <hip/hip_fp16.h>

// Pipeline:
//  x (4,64,130,130) --conv3x3 valid + bias + maxpool2x2--> p1 (4,64,64,64)
//  p1 --1x1 conv (64->32)--> t2 (4,32,64,64)
//  t2 --3x3 conv pad=1 (32->32)--> t3 (4,32,64,64)
//  t3 --1x1 conv (32->1152)--> t4h[b][strip][chunk][ckk][16 po]  fp16 (oy,ox)
//  deform_conv(x, upsample2x(offsets), wd) -> out (4,64,128,128)
//  Deform (MFMA v2): block = 16-po strip (64 px). Phase-1 fills a bf16 A-tile
//  [64 px][288 K] with bilinear samples, barrier every 16 channels (L2
//  locality window, R9 cadence). XOR-swizzled A layout (pitch 320 shorts,
//  pb = (col>>3)^(row&7)) -> conflict-free-ish stores AND balanced b128 reads.
//  Phase-2: D[64px][64oc] += V.W^T via mfma_f32_16x16x32_bf16 (9 ks x 4 n per
//  half). Epilogue staged through LDS -> coalesced stores (fixes R12's 232 MB).

#define HX 130
#define WX 130

typedef short bf16x8 __attribute__((ext_vector_type(8)));
typedef float f32x4 __attribute__((ext_vector_type(4)));

static __device__ __forceinline__ unsigned short f2bf(float f) {
    unsigned u = __float_as_uint(f);
    unsigned r = u + 0x7fff + ((u >> 16) & 1);   // round-to-nearest-even
    return (unsigned short)(r >> 16);
}

// A-tile address (in shorts): row pitch 320, 16B-block swizzle
static __device__ __forceinline__ int aoff(int row, int col) {
    return row * 320 + ((((col >> 3) ^ (row & 7))) << 3) + (col & 7);
}

// ---------------- K0: wd (o,c,3,3) -> bf16 wdtb[h(2)][oc(64)][col(288)]
// col = sl*144 + lc*72 + ch*9 + kk for c = h*32 + sl*16 + lc*8 + ch
__global__ __launch_bounds__(256) void k_wdt(const float* __restrict__ wd,
                                             unsigned short* __restrict__ wdtb) {
    int idx = blockIdx.x * 256 + threadIdx.x;   // 64*64*9 = 36864
    if (idx >= 36864) return;
    int o = idx / 576;
    int rem = idx - o * 576;
    int c = rem / 9;
    int kk = rem - c * 9;
    int h = c >> 5;
    int c5 = c & 31;
    int col = (c5 >> 4) * 144 + ((c5 >> 3) & 1) * 72 + (c5 & 7) * 9 + kk;
    wdtb[(size_t)(h * 64 + o) * 288 + col] = f2bf(wd[idx]);
}

// ---------------- K1: conv3x3 valid (64->64) + bias + maxpool 2x2 -> p1
// grid 1024 = b(4) * cog(16, 4 oc) * tile(16, 4 pooled rows); block 256
__global__ __launch_bounds__(256, 4) void k_conv0_pool(const float* __restrict__ x,
                                                       const float* __restrict__ w0,
                                                       const float* __restrict__ b0,
                                                       float* __restrict__ p1) {
    int idx = blockIdx.x;
    int tile = idx & 15;          // 4 pooled rows each
    int cog = (idx >> 4) & 15;    // blockIdx-derived -> weight loads scalar
    int b = idx >> 8;
    int tid = threadIdx.x;
    int pw = tid & 63;
    int phl = tid >> 6;           // 0..3
    int ph = tile * 4 + phl;
    __shared__ float slab[2][10 * WX];        // 2 ci x 1300 floats
    const float* xb = x + (size_t)(b * 64) * HX * WX;
    int row0 = tile * 8;          // x rows row0..row0+9
    const float* xbase = xb + row0 * WX;
    float acc[4][4];
    #pragma unroll
    for (int i = 0; i < 4; ++i)
        #pragma unroll
        for (int j = 0; j < 4; ++j) acc[i][j] = 0.f;

    float pre[11];
    #pragma unroll
    for (int j = 0; j < 11; ++j) {
        int i = tid + j * 256;    // 0..2599 covers both ci slabs
        int ci = i / 1300, off = i - ci * 1300;
        pre[j] = (i < 2600) ? xbase[(size_t)ci * (HX * WX) + off] : 0.f;
    }

    for (int cg = 0; cg < 32; ++cg) {         // 2 ci per stage
        __syncthreads();
        #pragma unroll
        for (int j = 0; j < 11; ++j) {
            int i = tid + j * 256;
            if (i < 2600) ((float*)slab)[i] = pre[j];
        }
        __syncthreads();
        if (cg < 31) {
            const float* xp = xbase + (size_t)(2 * cg + 2) * (HX * WX);
            #pragma unroll
            for (int j = 0; j < 11; ++j) {
                int i = tid + j * 256;
                int ci = i / 1300, off = i - ci * 1300;
                pre[j] = (i < 2600) ? xp[(size_t)ci * (HX * WX) + off] : 0.f;
            }
        }
        #pragma unroll
        for (int lc = 0; lc < 2; ++lc) {
            int ci = 2 * cg + lc;
            float v[4][4];
            #pragma unroll
            for (int r2 = 0; r2 < 4; ++r2) {
                const float* rp = &slab[lc][(2 * phl + r2) * WX + 2 * pw];
                float2 a = *(const float2*)rp;
                float2 bb = *(const float2*)(rp + 2);
                v[r2][0] = a.x; v[r2][1] = a.y; v[r2][2] = bb.x; v[r2][3] = bb.y;
            }
            #pragma unroll
            for (int i = 0; i < 4; ++i) {
                const float* wp = w0 + (((cog * 4 + i) * 64) + ci) * 9;  // uniform
                float w[9];
                #pragma unroll
                for (int k = 0; k < 9; ++k) w[k] = wp[k];
                #pragma unroll
                for (int dr = 0; dr < 2; ++dr)
                    #pragma unroll
                    for (int dc = 0; dc < 2; ++dc) {
                        float s = acc[i][dr * 2 + dc];
                        #pragma unroll
                        for (int ky = 0; ky < 3; ++ky)
                            #pragma unroll
                            for (int kx = 0; kx < 3; ++kx)
                                s += w[ky * 3 + kx] * v[dr + ky][dc + kx];
                        acc[i][dr * 2 + dc] = s;
                    }
            }
        }
    }
    #pragma unroll
    for (int i = 0; i < 4; ++i) {
        float m = fmaxf(fmaxf(acc[i][0], acc[i][1]), fmaxf(acc[i][2], acc[i][3]))
                + b0[cog * 4 + i];
        p1[(((size_t)b * 64 + cog * 4 + i) * 64 + ph) * 64 + pw] = m;
    }
}

// ---------------- K2: 1x1 conv 64->32 on 64x64; grid 1024 (2 oc/thread)
__global__ __launch_bounds__(256) void k_conv1x1_a(const float* __restrict__ p1,
                                                   const float* __restrict__ w1,
                                                   const float* __restrict__ b1,
                                                   float* __restrict__ t2) {
    int blk = blockIdx.x;
    int pt = blk & 15;
    int cog = (blk >> 4) & 15;
    int b = blk >> 8;
    int p = pt * 256 + threadIdx.x;
    float acc[2];
    #pragma unroll
    for (int i = 0; i < 2; ++i) acc[i] = b1[cog * 2 + i];
    const float* ip = p1 + (size_t)b * 64 * 4096 + p;
    for (int ci = 0; ci < 64; ++ci) {
        float v = ip[(size_t)ci * 4096];
        #pragma unroll
        for (int i = 0; i < 2; ++i) acc[i] += w1[(cog * 2 + i) * 64 + ci] * v;
    }
    float* op = t2 + (size_t)b * 32 * 4096 + p;
    #pragma unroll
    for (int i = 0; i < 2; ++i) op[(size_t)(cog * 2 + i) * 4096] = acc[i];
}

// ---------------- K3: 3x3 conv pad=1, 32->32 on 64x64; grid 1024 (2 oc/thread)
__global__ __launch_bounds__(256) void k_conv3x3_b(const float* __restrict__ t2,
                                                   const float* __restrict__ w2,
                                                   const float* __restrict__ b2,
                                                   float* __restrict__ t3) {
    int blk = blockIdx.x;
    int pt = blk & 15;
    int cog = (blk >> 4) & 15;
    int b = blk >> 8;
    int p = pt * 256 + threadIdx.x;
    int hy = p >> 6, wx = p & 63;
    float acc[2];
    #pragma unroll
    for (int i = 0; i < 2; ++i) acc[i] = b2[cog * 2 + i];
    const float* ip = t2 + (size_t)b * 32 * 4096;
    for (int ci = 0; ci < 32; ++ci) {
        float v[9];
        #pragma unroll
        for (int ky = 0; ky < 3; ++ky) {
            int yy = hy + ky - 1;
            #pragma unroll
            for (int kx = 0; kx < 3; ++kx) {
                int xx = wx + kx - 1;
                bool ok = (yy >= 0 && yy < 64 && xx >= 0 && xx < 64);
                int yc = min(max(yy, 0), 63), xc = min(max(xx, 0), 63);
                float val = ip[(size_t)ci * 4096 + yc * 64 + xc];
                v[ky * 3 + kx] = ok ? val : 0.f;
            }
        }
        #pragma unroll
        for (int i = 0; i < 2; ++i) {
            const float* wp = w2 + (((cog * 2 + i) * 32) + ci) * 9;   // uniform
            float s = acc[i];
            #pragma unroll
            for (int k = 0; k < 9; ++k) s += wp[k] * v[k];
            acc[i] = s;
        }
    }
    float* op = t3 + (size_t)b * 32 * 4096 + p;
    #pragma unroll
    for (int i = 0; i < 2; ++i) op[(size_t)(cog * 2 + i) * 4096] = acc[i];
}

// ---------------- K4: 1x1 conv 32->1152 -> fp16 (oy,ox)-paired strip-blocked
// t4h[b][strip][chunk(8)][ckk(72)][po(16)] as __half2.  grid 4608.
__global__ __launch_bounds__(256) void k_conv1x1_off(const float* __restrict__ t3,
                                                     const float* __restrict__ w3,
                                                     const float* __restrict__ b3,
                                                     __half2* __restrict__ t4h) {
    int blk = blockIdx.x;
    int pt = blk & 15;
    int rem = blk >> 4;           // 0..287
    int chg = rem % 72;           // blockIdx-derived -> scalar weight loads
    int b = rem / 72;
    int p = pt * 256 + threadIdx.x;
    float v[32];
    const float* ip = t3 + (size_t)b * 32 * 4096 + p;
    #pragma unroll
    for (int ci = 0; ci < 32; ++ci) v[ci] = ip[(size_t)ci * 4096];
    int strip = p >> 4, pl = p & 15;
    __half2* base = t4h + (size_t)(b * 256 + strip) * 9216;   // 8*1152 half2
    #pragma unroll
    for (int m = 0; m < 8; ++m) {
        int chE = chg * 16 + 2 * m;
        float accE = b3[chE], accO = b3[chE + 1];
        const float* wpE = w3 + chE * 32;         // uniform
        const float* wpO = wpE + 32;
        #pragma unroll
        for (int ci = 0; ci < 32; ++ci) {
            accE += wpE[ci] * v[ci];
            accO += wpO[ci] * v[ci];
        }
        int gp = chg * 8 + m;                     // global pair 0..575
        int chunk = gp / 72;
        int ckk = gp - chunk * 72;
        base[chunk * 1152 + ckk * 16 + pl] = __floats2half2_rn(accE, accO);
    }
}

// ---------------- K5: deformable conv, MFMA phase-2 (v2)
// grid 1024 = strip(256)*4 + b. block 256 = 4 waves; wave w owns px rows
// w*16..w*16+15. Per half h: 2 phase-1 sub-phases (16 ch each, barrier
// between) fill A cols 0..287; then 9 K-steps x 4 N-tiles of MFMA.
__global__ __launch_bounds__(256, 4) void k_deform(const float* __restrict__ x,
                                                   const __half2* __restrict__ t4h,
                                                   const unsigned short* __restrict__ wdtb,
                                                   float* __restrict__ out) {
    int blk = blockIdx.x;
    int b = blk & 3;
    int strip = blk >> 2;         // 0..255
    int tid = threadIdx.x;
    int po0 = strip * 16;
    int qy = po0 >> 6;            // strip lies in one quad-row
    int qx0 = po0 & 63;
    int w = tid >> 6;             // wave id
    int lane = tid & 63;
    int lm = lane & 15;
    int lq = lane >> 4;

    __shared__ __align__(16) unsigned short alds[64 * 320];   // 40960 B

    f32x4 acc[4];
    #pragma unroll
    for (int n = 0; n < 4; ++n) acc[n] = (f32x4){0.f, 0.f, 0.f, 0.f};

    const float* xb = x + (size_t)b * 64 * HX * WX;
    const __half2* osrc = t4h + (size_t)(b * 256 + strip) * 9216;

    for (int h = 0; h < 2; ++h) {
        #pragma unroll 1
        for (int sl = 0; sl < 2; ++sl) {
            int s = h * 2 + sl;           // sup = 16 channels
            __syncthreads();              // alds free (prev phase-2 done) + phase-lock
            // offsets for this sup: 2304 half2, fully coalesced
            __half2 o2h[9];
            #pragma unroll
            for (int it = 0; it < 9; ++it)
                o2h[it] = osrc[s * 2304 + it * 256 + tid];
            // ---- phase 1: 2304 tasks (16 tq x 144 kcol)
            #pragma unroll
            for (int it = 0; it < 9; ++it) {
                int idx = it * 256 + tid;     // 0..2303
                int tq = idx & 15;
                int kcol = idx >> 4;          // 0..143
                int lc = kcol >= 72;
                int ckk = kcol - 72 * lc;     // 0..71
                int ch = (ckk * 57) >> 9;     // /9
                int kk = ckk - ch * 9;
                int c = s * 16 + lc * 8 + ch;
                int clocal = sl * 144 + kcol; // A column 0..287
                float2 off = __half22float2(o2h[it]);
                float py = off.x + (float)(2 * qy + kk / 3);
                float px = off.y + (float)(2 * (qx0 + tq) + kk % 3);
                float y0f = floorf(py), x0f = floorf(px);
                float fy = py - y0f, fx = px - x0f;
                int y0 = (int)y0f, x0 = (int)x0f;
                const float* xp = xb + (size_t)c * (HX * WX);
                float t[3][3];
                #pragma unroll
                for (int r = 0; r < 3; ++r) {
                    int yy = y0 + r;
                    bool vy = (yy >= 0) & (yy < HX);
                    int yc = min(max(yy, 0), HX - 1);
                    #pragma unroll
                    for (int sx = 0; sx < 3; ++sx) {
                        int xx = x0 + sx;
                        bool vx = (xx >= 0) & (xx < WX);
                        int xc = min(max(xx, 0), WX - 1);
                        float val = xp[yc * WX + xc];
                        t[r][sx] = (vy & vx) ? val : 0.f;
                    }
                }
                float h0[3], h1[3];
                #pragma unroll
                for (int r = 0; r < 3; ++r) {
                    h0[r] = t[r][0] + fx * (t[r][1] - t[r][0]);
                    h1[r] = t[r][1] + fx * (t[r][2] - t[r][1]);
                }
                alds[aoff(0 * 16 + tq, clocal)] = f2bf(h0[0] + fy * (h0[1] - h0[0]));
                alds[aoff(1 * 16 + tq, clocal)] = f2bf(h1[0] + fy * (h1[1] - h1[0]));
                alds[aoff(2 * 16 + tq, clocal)] = f2bf(h0[1] + fy * (h0[2] - h0[1]));
                alds[aoff(3 * 16 + tq, clocal)] = f2bf(h1[1] + fy * (h1[2] - h1[1]));
            }
        }
        __syncthreads();          // A-tile (288 cols) visible

        // ---- phase 2: D[64px][64oc] += V[64][288] . W^T  (MFMA)
        int arow = w * 16 + lm;
        const unsigned short* bbase = wdtb + (size_t)(h * 64) * 288;
        #pragma unroll
        for (int ks = 0; ks < 9; ++ks) {
            bf16x8 a = *(const bf16x8*)&alds[aoff(arow, ks * 32 + lq * 8)];
            #pragma unroll
            for (int n = 0; n < 4; ++n) {
                bf16x8 bb = *(const bf16x8*)(bbase + (size_t)(n * 16 + lm) * 288
                                             + ks * 32 + lq * 8);
                acc[n] = __builtin_amdgcn_mfma_f32_16x16x32_bf16(a, bb, acc[n], 0, 0, 0);
            }
        }
    }

    // ---- epilogue via LDS: D lane layout -> [oc][px] -> coalesced stores
    __syncthreads();              // all phase-2 reads of alds complete
    float* dlds = (float*)alds;   // 64*65 = 4160 floats (16.6 KB of 40.9)
    #pragma unroll
    for (int n = 0; n < 4; ++n) {
        int oc = n * 16 + lm;
        #pragma unroll
        for (int r = 0; r < 4; ++r) {
            int px = w * 16 + lq * 4 + r;     // = sub*16 + q
            dlds[oc * 65 + px] = acc[n][r];
        }
    }
    __syncthreads();
    {
        int oc = tid >> 2;
        int sy = (tid >> 1) & 1;
        int qh = (tid & 1) * 8;
        float* orow = out + (((size_t)b * 64 + oc) * 128 + 2 * qy + sy) * 128 + 2 * qx0;
        const float* d0 = &dlds[oc * 65 + (sy * 2 + 0) * 16];
        const float* d1 = &dlds[oc * 65 + (sy * 2 + 1) * 16];
        #pragma unroll
        for (int i = 0; i < 8; ++i) {
            int q = qh + i;
            *(float2*)(orow + 2 * q) = make_float2(d0[q], d1[q]);
        }
    }
}

extern "C" void kernel_launch(void* const* d_in, const int* in_sizes, int n_in,
                              void* d_out, int out_size, void* d_ws, size_t ws_size,
                              hipStream_t stream) {
    const float* x  = (const float*)d_in[0];
    const float* w0 = (const float*)d_in[1];
    const float* b0 = (const float*)d_in[2];
    const float* w1 = (const float*)d_in[3];
    const float* b1 = (const float*)d_in[4];
    const float* w2 = (const float*)d_in[5];
    const float* b2 = (const float*)d_in[6];
    const float* w3 = (const float*)d_in[7];
    const float* b3 = (const float*)d_in[8];
    const float* wd = (const float*)d_in[9];
    float* out = (float*)d_out;

    float* ws = (float*)d_ws;
    float* p1    = ws;                       // 1,048,576 floats
    float* t2    = p1 + 1048576;             //   524,288
    float* t3    = t2 + 524288;              //   524,288
    __half2* t4h = (__half2*)(t3 + 524288);  // 9,437,184 half2 (37.7 MB)
    unsigned short* wdtb = (unsigned short*)(t4h + 9437184);  // 36,864 bf16

    k_wdt<<<144, 256, 0, stream>>>(wd, wdtb);
    k_conv0_pool<<<1024, 256, 0, stream>>>(x, w0, b0, p1);
    k_conv1x1_a<<<1024, 256, 0, stream>>>(p1, w1, b1, t2);
    k_conv3x3_b<<<1024, 256, 0, stream>>>(t2, w2, b2, t3);
    k_conv1x1_off<<<4608, 256, 0, stream>>>(t3, w3, b3, t4h);
    k_deform<<<1024, 256, 0, stream>>>(x, t4h, wdtb, out);
}